// Round 9
// baseline (6394.604 us; speedup 1.0000x reference)
//
#include <hip/hip_runtime.h>
#include <hip/hip_fp16.h>

// LSTM B=8192 S=1024 H=256 — round 9: in-wave MFMA/VALU software pipeline.
// r8 proved phase_time = VALU_time + MFMA_time (pipes serialized: all waves
// do K-loop then elementwise in chip-wide lockstep). Fix: 4 sets of 16 rows
// per pair {B,B^8}; iteration (s,t) runs K-loop MFMAs of set s INTERLEAVED
// with elementwise+publish of set s-1 (independent registers -> scheduler
// fills each pipe's shadow with the other stream).
// 256 blocks x 512 thr, 1 block/CU. Each block owns j-half (128 j): wfrag
// 128 regs STATIC-indexed. Rotation gives each publish -> peer-DMA link a
// 2-sub (~1.2us) slack. acc ping-pong (A/B) = 32 regs; w0/bias unpacked
// once outside the loop. One barrier per sub-iteration.

typedef _Float16 f16x8 __attribute__((ext_vector_type(8)));
typedef float f32x4 __attribute__((ext_vector_type(4)));
typedef unsigned int u32;
typedef unsigned short u16;

#define WINT_OFF 0u
#define W0B_OFF  524288u
#define FLAG_OFF 528384u   // int[256 blocks][4 sets][16] = 64 KB
#define PUB_OFF  1048576u  // u16[(set*2+par)*128 + pair][4096] = 8 MB

static __device__ __forceinline__ float fast_exp2(float x) {
#if __has_builtin(__builtin_amdgcn_exp2f)
  return __builtin_amdgcn_exp2f(x);
#else
  return exp2f(x);
#endif
}
static __device__ __forceinline__ float fast_rcp(float x) {
#if __has_builtin(__builtin_amdgcn_rcpf)
  return __builtin_amdgcn_rcpf(x);
#else
  return 1.0f / x;
#endif
}
static __device__ __forceinline__ float fsig(float x) {
  return fast_rcp(1.0f + fast_exp2(-1.44269504f * x));
}
static __device__ __forceinline__ float ftanh_(float x) {
  float e = fast_exp2(2.88539008f * x);
  return 1.0f - 2.0f * fast_rcp(e + 1.0f);
}
static __device__ __forceinline__ u16 f16b(float f) {
  union { _Float16 h; u16 u; } cv; cv.h = (_Float16)f; return cv.u;
}
static __device__ __forceinline__ float h2f(u16 u) {
  union { u16 u; _Float16 h; } cv; cv.u = u; return (float)cv.h;
}

// Wint[n][k], n = g*256 + j; w0b[n] = packed fp16 {w0, bias}.
__global__ void lstm_prep(const float* __restrict__ Wf, const float* __restrict__ Wi,
                          const float* __restrict__ Wc, const float* __restrict__ Wo,
                          const float* __restrict__ bf_, const float* __restrict__ bi_,
                          const float* __restrict__ bc_, const float* __restrict__ bo_,
                          u16* __restrict__ Wint, u32* __restrict__ w0b) {
  int n = blockIdx.x;       // 0..1023
  int k = threadIdx.x;      // 0..255
  int g = n >> 8, j = n & 255;
  const float* Ws = (g == 0) ? Wf : (g == 1) ? Wi : (g == 2) ? Wc : Wo;
  Wint[n * 256 + k] = f16b(Ws[j * 257 + 1 + k]);
  if (k == 0) {
    const float* bs = (g == 0) ? bf_ : (g == 1) ? bi_ : (g == 2) ? bc_ : bo_;
    w0b[n] = (u32)f16b(Ws[j * 257]) | ((u32)f16b(bs[j]) << 16);
  }
}

// Zero parity-0 pub of all 4 sets (h_0 = 0), flags (64 KB), out = bout.
__global__ void lstm_zero(uint4* __restrict__ pub4, uint4* __restrict__ flags4,
                          float* __restrict__ out, const float* __restrict__ bout) {
  int idx = blockIdx.x * 256 + threadIdx.x;
  uint4 z = uint4{0, 0, 0, 0};
  if (idx < 262144) {                      // 4 sets x 1 MB parity-0 images
    int s = idx >> 16, off = idx & 65535;
    pub4[(size_t)s * 131072 + off] = z;
  } else if (idx < 266240) flags4[idx - 262144] = z;
  else { int o = idx - 266240; if (o < 8192) out[o] = bout[0]; }
}

__global__ __launch_bounds__(512, 2) void lstm_main(
    const u16* __restrict__ Wint, const u32* __restrict__ w0b,
    const float* __restrict__ x, const float* __restrict__ Wout,
    float* __restrict__ out, u16* __restrict__ pub, int* __restrict__ flags) {

  __shared__ __align__(16) u16 stg[4][4096];  // [set][16 b][256 k] swizzled

  const int tid  = threadIdx.x;
  const int wv   = tid >> 6;
  const int lane = tid & 63;
  const int l15  = lane & 15;
  const int quad = lane >> 4;
  const int B    = blockIdx.x;
  const int mi   = (B >> 3) & 1;
  const int peer = B ^ 8;
  const int pid  = (B & 7) | ((B >> 4) << 3);   // pair 0..127
  const int rows0 = pid * 64;
  const int j0w  = mi * 128 + wv * 16;          // wave's global j base

  // ---- one-time: W A-fragments (128 regs, STATIC reg indices) ----
  f16x8 wfrag[4][8];
#pragma unroll
  for (int g = 0; g < 4; ++g)
#pragma unroll
    for (int ks = 0; ks < 8; ++ks)
      wfrag[g][ks] = *(const f16x8*)(Wint +
          (size_t)(g * 256 + j0w + l15) * 256 + ks * 32 + quad * 8);
  // w0/bias for this thread's 4 j's (j = j0w + quad*4 + r), unpacked ONCE
  float w0f[4][4], bsf[4][4];
#pragma unroll
  for (int g = 0; g < 4; ++g)
#pragma unroll
    for (int r = 0; r < 4; ++r) {
      u32 pk = w0b[g * 256 + j0w + quad * 4 + r];
      w0f[g][r] = h2f((u16)pk); bsf[g][r] = h2f((u16)(pk >> 16));
    }

  // zero stg (h_0 images): 32 KB
#pragma unroll
  for (int i = 0; i < 4; ++i) ((uint4*)stg)[tid + i * 512] = uint4{0, 0, 0, 0};

  float cst[4][4];              // [set][r], b = l15
#pragma unroll
  for (int s = 0; s < 4; ++s)
#pragma unroll
    for (int r = 0; r < 4; ++r) cst[s][r] = 0.0f;

  const float* xq = x + (size_t)rows0 * 1024;
  float xcur[4];
#pragma unroll
  for (int s = 0; s < 4; ++s) xcur[s] = xq[(size_t)(s * 16 + l15) * 1024];

  f32x4 accA[4], accB[4];

  __syncthreads();

  // SUBSTEP(S, ACC, PREV, SP, TP1, GUARD, SN, TN, DGUARD):
  // K-loop for (S,t) into ACC; elementwise+publish of (SP, t'=TP1-1) from PREV.
#define SUBSTEP(S, ACC, PREV, SP, TP1, GUARD, SN, TN, DGUARD)                     \
  do {                                                                            \
    f16x8 bb0[4], bb1[4];                                                         \
    _Pragma("unroll")                                                             \
    for (int ks = 0; ks < 4; ++ks) {                                              \
      int c = (ks * 4 + quad) ^ (l15 & 7);                                        \
      bb0[ks] = *(const f16x8*)(&stg[S][0] + l15 * 256 + c * 8);                  \
    }                                                                             \
    /* elementwise of prev set (independent of the MFMA stream) */                \
    if (GUARD) {                                                                  \
      float hv4[4];                                                               \
      _Pragma("unroll")                                                           \
      for (int r = 0; r < 4; ++r) {                                               \
        float fg = PREV[0][r], ig = PREV[1][r];                                   \
        float cg = PREV[2][r], og = PREV[3][r];                                   \
        float c_ = fsig(fg) * cst[SP][r] + fsig(ig) * ftanh_(cg);                 \
        cst[SP][r] = c_;                                                          \
        hv4[r] = fsig(og) * ftanh_(c_);                                           \
      }                                                                           \
      u32 lo = (u32)f16b(hv4[0]) | ((u32)f16b(hv4[1]) << 16);                     \
      u32 hi = (u32)f16b(hv4[2]) | ((u32)f16b(hv4[3]) << 16);                     \
      u16* pb = pub + ((size_t)(((SP) * 2 + ((TP1) & 1)) * 128 + pid)) * 4096;    \
      int cpub = (mi * 16 + wv * 2 + (quad >> 1)) ^ (l15 & 7);                    \
      *(uint2*)(pb + l15 * 256 + cpub * 8 + (quad & 1) * 4) = uint2{lo, hi};      \
    }                                                                             \
    /* acc init + x prefetch */                                                   \
    _Pragma("unroll")                                                             \
    for (int g = 0; g < 4; ++g)                                                   \
      _Pragma("unroll")                                                           \
      for (int r = 0; r < 4; ++r)                                                 \
        ACC[g][r] = xcur[S] * w0f[g][r] + bsf[g][r];                              \
    xcur[S] = xq[(size_t)((S) * 16 + l15) * 1024 + ((t + 1) & 1023)];             \
    /* MFMA K-loop */                                                             \
    _Pragma("unroll")                                                             \
    for (int ks = 0; ks < 4; ++ks)                                                \
      _Pragma("unroll")                                                           \
      for (int g = 0; g < 4; ++g)                                                 \
        ACC[g] = __builtin_amdgcn_mfma_f32_16x16x32_f16(                          \
            wfrag[g][ks], bb0[ks], ACC[g], 0, 0, 0);                              \
    _Pragma("unroll")                                                             \
    for (int ks = 4; ks < 8; ++ks) {                                              \
      int c = (ks * 4 + quad) ^ (l15 & 7);                                        \
      bb1[ks - 4] = *(const f16x8*)(&stg[S][0] + l15 * 256 + c * 8);              \
    }                                                                             \
    _Pragma("unroll")                                                             \
    for (int ks = 4; ks < 8; ++ks)                                                \
      _Pragma("unroll")                                                           \
      for (int g = 0; g < 4; ++g)                                                 \
        ACC[g] = __builtin_amdgcn_mfma_f32_16x16x32_f16(                          \
            wfrag[g][ks], bb1[ks - 4], ACC[g], 0, 0, 0);                          \
    /* poll + DMA next set's h image (2-sub slack on the link) */                 \
    if (DGUARD) {                                                                 \
      while (__hip_atomic_load(flags + (peer * 4 + (SN)) * 16, __ATOMIC_RELAXED,  \
                               __HIP_MEMORY_SCOPE_AGENT) < (TN))                  \
        __builtin_amdgcn_s_sleep(1);                                              \
      const u16* src = pub + ((size_t)(((SN) * 2 + ((TN) & 1)) * 128 + pid)) * 4096; \
      __builtin_amdgcn_global_load_lds(                                           \
          (const __attribute__((address_space(1))) u32*)(src + wv * 512 + lane * 8), \
          (__attribute__((address_space(3))) u32*)(&stg[SN][0] + wv * 512), 16, 0, 0); \
    }                                                                             \
    __syncthreads();                                                              \
    if (tid == 0 && (GUARD))                                                      \
      __hip_atomic_store(flags + (B * 4 + (SP)) * 16, (TP1), __ATOMIC_RELAXED,    \
                         __HIP_MEMORY_SCOPE_AGENT);                               \
  } while (0)

#pragma unroll 1
  for (int t = 0; t < 1024; ++t) {
    SUBSTEP(0, accA, accB, 3, t,     (t > 0), 1, t,     true);
    SUBSTEP(1, accB, accA, 0, t + 1, true,    2, t,     true);
    SUBSTEP(2, accA, accB, 1, t + 1, true,    3, t,     true);
    SUBSTEP(3, accB, accA, 2, t + 1, true,    0, t + 1, (t < 1023));
  }

  // ---- epilogue: elementwise+publish of (set 3, t=1023) from accB ----
  {
    float hv4[4];
#pragma unroll
    for (int r = 0; r < 4; ++r) {
      float fg = accB[0][r], ig = accB[1][r];
      float cg = accB[2][r], og = accB[3][r];
      float c_ = fsig(fg) * cst[3][r] + fsig(ig) * ftanh_(cg);
      hv4[r] = fsig(og) * ftanh_(c_);
    }
    u32 lo = (u32)f16b(hv4[0]) | ((u32)f16b(hv4[1]) << 16);
    u32 hi = (u32)f16b(hv4[2]) | ((u32)f16b(hv4[3]) << 16);
    u16* pb = pub + ((size_t)((3 * 2 + 0) * 128 + pid)) * 4096;   // parity 0
    int cpub = (mi * 16 + wv * 2 + (quad >> 1)) ^ (l15 & 7);
    *(uint2*)(pb + l15 * 256 + cpub * 8 + (quad & 1) * 4) = uint2{lo, hi};
  }
  __syncthreads();   // drain publish stores

  // ---- out[b] += (own j-half of h_1024) . Wout  (out pre-set to bout) ----
  if (tid < 64) {
    int s = tid >> 4, b = tid & 15;
    const u16* pbase = pub + ((size_t)((s * 2 + 0) * 128 + pid)) * 4096;
    float a = 0.0f;
#pragma unroll
    for (int lc = 0; lc < 16; ++lc) {
      int cp = (mi * 16 + lc) ^ (b & 7);
      f16x8 hv = *(const f16x8*)(pbase + b * 256 + cp * 8);
#pragma unroll
      for (int e = 0; e < 8; ++e) a += (float)hv[e] * Wout[mi * 128 + lc * 8 + e];
    }
    atomicAdd(&out[rows0 + s * 16 + b], a);
  }
#undef SUBSTEP
}

extern "C" void kernel_launch(void* const* d_in, const int* in_sizes, int n_in,
                              void* d_out, int out_size, void* d_ws, size_t ws_size,
                              hipStream_t stream) {
  const float* x    = (const float*)d_in[0];
  const float* Wf   = (const float*)d_in[1];
  const float* bf_  = (const float*)d_in[2];
  const float* Wi   = (const float*)d_in[3];
  const float* bi_  = (const float*)d_in[4];
  const float* Wc   = (const float*)d_in[5];
  const float* bc_  = (const float*)d_in[6];
  const float* Wo   = (const float*)d_in[7];
  const float* bo_  = (const float*)d_in[8];
  const float* Wout = (const float*)d_in[9];
  const float* bout = (const float*)d_in[10];

  u16* Wint  = (u16*)((char*)d_ws + WINT_OFF);
  u32* w0b   = (u32*)((char*)d_ws + W0B_OFF);
  int* flags = (int*)((char*)d_ws + FLAG_OFF);
  u16* pub   = (u16*)((char*)d_ws + PUB_OFF);

  lstm_prep<<<1024, 256, 0, stream>>>(Wf, Wi, Wc, Wo, bf_, bi_, bc_, bo_, Wint, w0b);
  lstm_zero<<<1072, 256, 0, stream>>>((uint4*)pub, (uint4*)flags, (float*)d_out, bout);
  lstm_main<<<256, 512, 0, stream>>>(Wint, w0b, x, Wout, (float*)d_out, pub, flags);
}